// Round 1
// baseline (5293.715 us; speedup 1.0000x reference)
//
#include <hip/hip_runtime.h>
#include <hip/hip_bf16.h>
#include <math.h>

// Problem constants
#define KF   7      // frames / groups
#define BB_  4      // batch
#define CC_  64     // channels per frame
#define HH   96
#define WW   96
#define HWSZ 9216   // 96*96
#define HEAD 256

// ---------------------------------------------------------------------------
// Weight transpose: w[co][ci][k] (k in 0..8) -> wT[(ci*9+k)*Cout + co]
// so phase-1 weight loads are lane-coalesced over co.
// ---------------------------------------------------------------------------
__global__ __launch_bounds__(256) void transpose_w(const float* __restrict__ w,
                                                   float* __restrict__ out,
                                                   int Cout, int Cin) {
    int e = blockIdx.x * 256 + threadIdx.x;
    int tot = Cout * Cin * 9;
    if (e >= tot) return;
    int co = e / (Cin * 9);
    int r  = e - co * (Cin * 9);
    int ci = r / 9;
    int k  = r - ci * 9;
    out[(size_t)(ci * 9 + k) * Cout + co] = w[e];
}

// ---------------------------------------------------------------------------
// Fused conv3x3(+bias)(+relu) -> optional conv1x1(+bias).
// Input is the features tensor (K,B,C,H,W) flattened; plane index for global
// input channel c of image `img`:  plane = (c>>6)*256 + img*64 + (c&63).
//   - wh/hm: Cin=64  -> plane = img*64 + c   (img = n for wh, 12+b for hm)
//   - id/off: Cin=448 -> plane = (k*4+b)*64 + c%64  with img=b
// mode: 0 = fused 1x1, out ch = img*Cf+cf
//       1 = fused 1x1, wh mapping: n=img, out ch = (n&3)*14 + (n>>2)*2 + cf
//       2 = raw store of Cmid channels (off conv, no relu, no 1x1)
// ---------------------------------------------------------------------------
#define TPX 32
__global__ __launch_bounds__(256) void conv3x3_fused(
    const float* __restrict__ X,
    const float* __restrict__ wT,   // [(ci*9+k)*Cmid + co]
    const float* __restrict__ b1,
    const float* __restrict__ w2,   // [cf*256 + co] (mode 0/1)
    const float* __restrict__ b2,
    float* __restrict__ out,
    int Cin, int Cmid, int Cf, int imgInOfs, int mode)
{
    __shared__ float sP[16][3][36];              // input patch chunk (16 ci)
    __shared__ __hip_bfloat16 sH[256][TPX + 1];  // hidden activations

    const int img  = blockIdx.y;
    const int tile = blockIdx.x;           // 0..287
    const int h0   = tile / 3;
    const int w0   = (tile % 3) * TPX;
    const int t    = threadIdx.x;
    const int imgIn = img + imgInOfs;

    float acc[TPX];
#pragma unroll
    for (int i = 0; i < TPX; ++i) acc[i] = 0.f;

    for (int ci0 = 0; ci0 < Cin; ci0 += 16) {
        __syncthreads();
        // cooperative patch load: 16 ci x 3 rows x 34 cols (zero-padded)
        for (int e = t; e < 16 * 102; e += 256) {
            int cc = e / 102;
            int r  = e - cc * 102;
            int ky = r / 34;
            int x  = r - ky * 34;
            int ci = ci0 + cc;
            int plane = ((ci >> 6) << 8) + imgIn * 64 + (ci & 63);
            int gh = h0 - 1 + ky;
            int gw = w0 - 1 + x;
            float v = 0.f;
            if ((unsigned)gh < (unsigned)HH && (unsigned)gw < (unsigned)WW)
                v = X[(size_t)plane * HWSZ + gh * WW + gw];
            sP[cc][ky][x] = v;
        }
        __syncthreads();

        if (t < Cmid) {
            const float* wbase = wT + (size_t)ci0 * 9 * Cmid + t;
            for (int cc = 0; cc < 16; ++cc) {
                const float* wr = wbase + (size_t)cc * 9 * Cmid;
                float wv[9];
#pragma unroll
                for (int j = 0; j < 9; ++j) wv[j] = wr[(size_t)j * Cmid];
#pragma unroll
                for (int ky = 0; ky < 3; ++ky) {
                    const float* rr = sP[cc][ky];
                    float rv[34];
#pragma unroll
                    for (int x = 0; x < 34; ++x) rv[x] = rr[x];
                    float k0 = wv[ky * 3 + 0];
                    float k1 = wv[ky * 3 + 1];
                    float k2 = wv[ky * 3 + 2];
#pragma unroll
                    for (int px = 0; px < TPX; ++px) {
                        acc[px] = fmaf(k0, rv[px],
                                  fmaf(k1, rv[px + 1],
                                  fmaf(k2, rv[px + 2], acc[px])));
                    }
                }
            }
        }
    }

    if (mode == 2) {
        // off conv: store raw conv+bias (no relu, no 1x1)
        if (t < Cmid) {
            float bbv = b1[t];
            float* op = out + ((size_t)(img * Cmid + t)) * HWSZ + h0 * WW + w0;
#pragma unroll
            for (int px = 0; px < TPX; ++px) op[px] = acc[px] + bbv;
        }
        return;
    }

    // bias + relu -> bf16 hidden in LDS
    if (t < Cmid) {
        float bbv = b1[t];
#pragma unroll
        for (int px = 0; px < TPX; ++px)
            sH[t][px] = __float2bfloat16(fmaxf(acc[px] + bbv, 0.f));
    }
    __syncthreads();

    // 1x1 conv over 256 hidden channels
    int total = Cf * TPX;
    for (int e = t; e < total; e += 256) {
        int cf = e >> 5;
        int px = e & (TPX - 1);
        float s = b2[cf];
        const float* wr = w2 + (size_t)cf * 256;
        for (int co = 0; co < 256; ++co)
            s = fmaf(wr[co], __bfloat162float(sH[co][px]), s);
        int och;
        if (mode == 1) {
            int bimg = img & 3;
            int kfr  = img >> 2;
            och = bimg * 14 + kfr * 2 + cf;
        } else {
            och = img * Cf + cf;
        }
        out[(size_t)och * HWSZ + h0 * WW + w0 + px] = s;
    }
}

// ---------------------------------------------------------------------------
// DCNv2 (modulated deformable conv) + bias + BN + ReLU + bz 1x1 conv, fused.
// Per block: one batch b, one 16-pixel row tile.
// Phase A: bilinear tap table (63 gk x 16 px): 4 clipped u16 idx + 4 weights
//          (weights pre-multiplied by validity and sigmoid mask).
// Phase B: per (g, 4-channel chunk): 144 threads build cols values in LDS,
//          then all 256 threads accumulate einsum (2 co x 8 px per thread).
// Phase C: bias+BN+relu -> bf16 LDS -> 1x1 conv to 16 bz channels.
// ---------------------------------------------------------------------------
#define DTP 16
__global__ __launch_bounds__(256) void dcn_bz(
    const float* __restrict__ X,        // features
    const float* __restrict__ offmap,   // ws: (B,189,H,W)
    const float* __restrict__ dwT,      // [(ci*9+k)*256 + co], ci = g*64+c
    const float* __restrict__ dcn_b,
    const float* __restrict__ bn_g, const float* __restrict__ bn_be,
    const float* __restrict__ bn_mn, const float* __restrict__ bn_vr,
    const float* __restrict__ bzw,      // [cf*256+co]
    const float* __restrict__ bzb,
    float* __restrict__ out_bz)
{
    __shared__ unsigned short sIdx[63 * DTP * 4];
    __shared__ float          sWt [63 * DTP * 4];
    __shared__ float          sV  [4][9][DTP];
    __shared__ __hip_bfloat16 sD  [256][DTP];

    const int b    = blockIdx.y;
    const int tile = blockIdx.x;       // 0..575
    const int h    = tile / 6;
    const int w0   = (tile % 6) * DTP;
    const int t    = threadIdx.x;

    const float* offp = offmap + (size_t)b * 189 * HWSZ;

    // ---- Phase A: tap table -------------------------------------------------
    for (int e = t; e < 63 * DTP; e += 256) {
        int gk = e >> 4;           // g*9+k
        int px = e & (DTP - 1);
        int k  = gk % 9;
        int pix = h * WW + w0 + px;
        float oy = offp[(size_t)gk * HWSZ + pix];
        float ox = offp[(size_t)(63 + gk) * HWSZ + pix];
        float mv = offp[(size_t)(126 + gk) * HWSZ + pix];
        float m  = 1.f / (1.f + expf(-mv));
        int ky = k / 3, kx = k - ky * 3;
        float sy = (float)(h - 1 + ky) + oy;
        float sx = (float)(w0 + px - 1 + kx) + ox;
        float fy = floorf(sy), fx = floorf(sx);
        float wy = sy - fy,    wx = sx - fx;
        int y0 = (int)fy, x0 = (int)fx;
        int y1 = y0 + 1,  x1 = x0 + 1;

        int base = e * 4;
        int   ys[4] = {y0, y0, y1, y1};
        int   xs[4] = {x0, x1, x0, x1};
        float ws4[4] = {(1.f - wy) * (1.f - wx), (1.f - wy) * wx,
                        wy * (1.f - wx),          wy * wx};
#pragma unroll
        for (int tp = 0; tp < 4; ++tp) {
            int yy = ys[tp], xx = xs[tp];
            bool valid = (yy >= 0) && (yy < HH) && (xx >= 0) && (xx < WW);
            int yc = min(max(yy, 0), HH - 1);
            int xc = min(max(xx, 0), WW - 1);
            sIdx[base + tp] = (unsigned short)(yc * WW + xc);
            sWt [base + tp] = valid ? ws4[tp] * m : 0.f;
        }
    }

    // ---- Phase B: einsum ----------------------------------------------------
    const int coA = t & 127;
    const int coB = coA + 128;
    const int pxh = (t >> 7) << 3;   // 0 or 8

    float acc0[8], acc1[8];
#pragma unroll
    for (int j = 0; j < 8; ++j) { acc0[j] = 0.f; acc1[j] = 0.f; }

    for (int g = 0; g < KF; ++g) {
        for (int c0 = 0; c0 < 64; c0 += 4) {
            __syncthreads();   // protect sV from previous iteration's readers
            if (t < 144) {
                int k  = t >> 4;        // 0..8
                int px = t & 15;
                int e4 = ((g * 9 + k) * DTP + px) * 4;
                ushort4 i4 = *(const ushort4*)&sIdx[e4];
                float4  w4 = *(const float4*)&sWt[e4];
                const float* pl = X + ((size_t)((g * BB_ + b) * CC_ + c0)) * HWSZ;
#pragma unroll
                for (int cc = 0; cc < 4; ++cc) {
                    const float* p = pl + (size_t)cc * HWSZ;
                    sV[cc][k][px] = w4.x * p[i4.x] + w4.y * p[i4.y] +
                                    w4.z * p[i4.z] + w4.w * p[i4.w];
                }
            }
            __syncthreads();
            const float* wr0 = dwT + ((size_t)(g * 64 + c0)) * 9 * 256;
            for (int cc = 0; cc < 4; ++cc) {
                const float* wr = wr0 + (size_t)cc * 9 * 256;
#pragma unroll
                for (int k = 0; k < 9; ++k) {
                    float wA = wr[k * 256 + coA];
                    float wB = wr[k * 256 + coB];
                    const float4* vp = (const float4*)&sV[cc][k][pxh];
                    float4 va = vp[0];
                    float4 vb = vp[1];
                    acc0[0] = fmaf(wA, va.x, acc0[0]);
                    acc0[1] = fmaf(wA, va.y, acc0[1]);
                    acc0[2] = fmaf(wA, va.z, acc0[2]);
                    acc0[3] = fmaf(wA, va.w, acc0[3]);
                    acc0[4] = fmaf(wA, vb.x, acc0[4]);
                    acc0[5] = fmaf(wA, vb.y, acc0[5]);
                    acc0[6] = fmaf(wA, vb.z, acc0[6]);
                    acc0[7] = fmaf(wA, vb.w, acc0[7]);
                    acc1[0] = fmaf(wB, va.x, acc1[0]);
                    acc1[1] = fmaf(wB, va.y, acc1[1]);
                    acc1[2] = fmaf(wB, va.z, acc1[2]);
                    acc1[3] = fmaf(wB, va.w, acc1[3]);
                    acc1[4] = fmaf(wB, vb.x, acc1[4]);
                    acc1[5] = fmaf(wB, vb.y, acc1[5]);
                    acc1[6] = fmaf(wB, vb.z, acc1[6]);
                    acc1[7] = fmaf(wB, vb.w, acc1[7]);
                }
            }
        }
    }

    // ---- bias + BN + relu -> bf16 LDS --------------------------------------
    {
        float scA = bn_g[coA] * rsqrtf(bn_vr[coA] + 1e-5f);
        float scB = bn_g[coB] * rsqrtf(bn_vr[coB] + 1e-5f);
        float mA = bn_mn[coA], mB = bn_mn[coB];
        float eA = bn_be[coA], eB = bn_be[coB];
        float dA = dcn_b[coA], dB = dcn_b[coB];
#pragma unroll
        for (int j = 0; j < 8; ++j) {
            float v = (acc0[j] + dA - mA) * scA + eA;
            sD[coA][pxh + j] = __float2bfloat16(fmaxf(v, 0.f));
            float u = (acc1[j] + dB - mB) * scB + eB;
            sD[coB][pxh + j] = __float2bfloat16(fmaxf(u, 0.f));
        }
    }
    __syncthreads();

    // ---- bz 1x1: 16 cf x 16 px = 256 threads --------------------------------
    {
        int cf = t >> 4;
        int px = t & 15;
        float s = bzb[cf];
        const float* wr = bzw + (size_t)cf * 256;
        for (int co = 0; co < 256; ++co)
            s = fmaf(wr[co], __bfloat162float(sD[co][px]), s);
        out_bz[((size_t)(b * 16 + cf)) * HWSZ + h * WW + w0 + px] = s;
    }
}

// ---------------------------------------------------------------------------
// Launch
// ---------------------------------------------------------------------------
extern "C" void kernel_launch(void* const* d_in, const int* in_sizes, int n_in,
                              void* d_out, int out_size, void* d_ws, size_t ws_size,
                              hipStream_t stream) {
    const float* feat   = (const float*)d_in[0];
    const float* hm_w1  = (const float*)d_in[1];
    const float* hm_b1  = (const float*)d_in[2];
    const float* hm_w2  = (const float*)d_in[3];
    const float* hm_b2  = (const float*)d_in[4];
    const float* wh_w1  = (const float*)d_in[5];
    const float* wh_b1  = (const float*)d_in[6];
    const float* wh_w2  = (const float*)d_in[7];
    const float* wh_b2  = (const float*)d_in[8];
    const float* id_w1  = (const float*)d_in[9];
    const float* id_b1  = (const float*)d_in[10];
    const float* id_w2  = (const float*)d_in[11];
    const float* id_b2  = (const float*)d_in[12];
    const float* off_w  = (const float*)d_in[13];
    const float* off_b  = (const float*)d_in[14];
    const float* dcn_w  = (const float*)d_in[15];
    const float* dcn_b  = (const float*)d_in[16];
    const float* bn_g   = (const float*)d_in[17];
    const float* bn_be  = (const float*)d_in[18];
    const float* bn_mn  = (const float*)d_in[19];
    const float* bn_vr  = (const float*)d_in[20];
    const float* bz_w   = (const float*)d_in[21];
    const float* bz_b   = (const float*)d_in[22];

    // Workspace layout (floats). Total ~40.4 MB.
    float* ws      = (float*)d_ws;
    float* off_out = ws;                      // 4*189*9216 = 6,967,296
    float* wh_wT   = off_out + 6967296;       // 64*9*256  =   147,456
    float* hm_wT   = wh_wT   + 147456;        //              147,456
    float* id_wT   = hm_wT   + 147456;        // 448*9*256 = 1,032,192
    float* off_wT  = id_wT   + 1032192;       // 448*9*189 =   762,048
    float* dcn_wT  = off_wT  + 762048;        //            1,032,192

    // Output layout (floats, concatenated): hm, bz, idout, owh
    float* out_hm = (float*)d_out;            // (4,24,96,96)  884,736
    float* out_bz = out_hm + 884736;          // (4,16,96,96)  589,824
    float* out_id = out_bz + 589824;          // (4,128,96,96) 4,718,592
    float* out_wh = out_id + 4718592;         // (4,14,96,96)  516,096

    // 1) weight transposes
    transpose_w<<<(147456 + 255) / 256, 256, 0, stream>>>(hm_w1, hm_wT, 256, 64);
    transpose_w<<<(147456 + 255) / 256, 256, 0, stream>>>(wh_w1, wh_wT, 256, 64);
    transpose_w<<<(1032192 + 255) / 256, 256, 0, stream>>>(id_w1, id_wT, 256, 448);
    transpose_w<<<(762048 + 255) / 256, 256, 0, stream>>>(off_w, off_wT, 189, 448);
    transpose_w<<<(1032192 + 255) / 256, 256, 0, stream>>>(dcn_w, dcn_wT, 256, 448);

    // 2) fused conv branches
    // wh: 28 images, mode 1 (wh output channel mapping)
    conv3x3_fused<<<dim3(288, 28), 256, 0, stream>>>(
        feat, wh_wT, wh_b1, wh_w2, wh_b2, out_wh, 64, 256, 2, 0, 1);
    // hm: images 12..15 (features[3]), mode 0
    conv3x3_fused<<<dim3(288, 4), 256, 0, stream>>>(
        feat, hm_wT, hm_b1, hm_w2, hm_b2, out_hm, 64, 256, 24, 12, 0);
    // id: cat input (Cin=448), mode 0
    conv3x3_fused<<<dim3(288, 4), 256, 0, stream>>>(
        feat, id_wT, id_b1, id_w2, id_b2, out_id, 448, 256, 128, 0, 0);
    // off: cat input, 189 raw channels to workspace, mode 2
    conv3x3_fused<<<dim3(288, 4), 256, 0, stream>>>(
        feat, off_wT, off_b, nullptr, nullptr, off_out, 448, 189, 0, 0, 2);

    // 3) DCN + BN + ReLU + bz (consumes off_out)
    dcn_bz<<<dim3(576, 4), 256, 0, stream>>>(
        feat, off_out, dcn_wT, dcn_b, bn_g, bn_be, bn_mn, bn_vr,
        bz_w, bz_b, out_bz);
}

// Round 2
// 3297.366 us; speedup vs baseline: 1.6054x; 1.6054x over previous
//
#include <hip/hip_runtime.h>
#include <hip/hip_bf16.h>
#include <math.h>

// Problem constants
#define KF   7      // frames / groups
#define BB_  4      // batch
#define CC_  64     // channels per frame
#define HH   96
#define WW   96
#define HWSZ 9216   // 96*96
#define HEAD 256

typedef __bf16 bf16x8 __attribute__((ext_vector_type(8)));
typedef __bf16 bf16x4 __attribute__((ext_vector_type(4)));
typedef float  f32x4  __attribute__((ext_vector_type(4)));

// ---------------------------------------------------------------------------
// Weight prep
// ---------------------------------------------------------------------------
// w[co][ci][k] fp32 -> wT2[(k*CoutPad + co)*Cin + ci] bf16 (ci contiguous)
__global__ __launch_bounds__(256) void cvt_taps(const float* __restrict__ w,
                                                __bf16* __restrict__ out,
                                                int Cout, int Cin, int CoutPad) {
    int e = blockIdx.x * 256 + threadIdx.x;
    int tot = Cout * Cin * 9;
    if (e >= tot) return;
    int co = e / (Cin * 9);
    int r  = e - co * (Cin * 9);
    int ci = r / 9;
    int k  = r - ci * 9;
    out[((size_t)k * CoutPad + co) * Cin + ci] = (__bf16)w[e];
}

// elementwise fp32 -> bf16 (same layout)
__global__ __launch_bounds__(256) void cvt_flat(const float* __restrict__ w,
                                                __bf16* __restrict__ out, int n) {
    int e = blockIdx.x * 256 + threadIdx.x;
    if (e < n) out[e] = (__bf16)w[e];
}

// w[co][ci][k] -> wT[(ci*9+k)*Cout + co] fp32 (for DCN kernel)
__global__ __launch_bounds__(256) void transpose_w(const float* __restrict__ w,
                                                   float* __restrict__ out,
                                                   int Cout, int Cin) {
    int e = blockIdx.x * 256 + threadIdx.x;
    int tot = Cout * Cin * 9;
    if (e >= tot) return;
    int co = e / (Cin * 9);
    int r  = e - co * (Cin * 9);
    int ci = r / 9;
    int k  = r - ci * 9;
    out[(size_t)(ci * 9 + k) * Cout + co] = w[e];
}

// ---------------------------------------------------------------------------
// MFMA conv3x3 (+bias,+relu) -> optional MFMA 1x1 (+bias).
// Block = one output row (96 px, 6 n-tiles of 16); 4 waves split co.
// MPW = m-tiles (16 co) per wave. MODE: 0 = 1x1 epilogue (och=img*Cf+cf),
// 1 = 1x1 epilogue wh mapping, 2 = raw store of conv+bias (Cf = #channels).
// Per-tap GEMM: B-fragment read directly from channels-last LDS tile.
// ---------------------------------------------------------------------------
template<int MPW, int MODE>
__global__ __launch_bounds__(256) void conv3x3_mfma(
    const float* __restrict__ X,
    const __bf16* __restrict__ wT2,   // [(tap*CmidPad + co)*Cin + ci]
    const float* __restrict__ b1,
    const __bf16* __restrict__ w2b,   // [cf*256 + co]
    const float* __restrict__ b2,
    float* __restrict__ out,
    int Cin, int CmidPad, int Cf, int imgInOfs)
{
    // LDS overlay: staging tile sX[3][98][40] bf16 (23520 B) and, for MODE<2,
    // hidden sH[96][264] bf16 (50688 B). Strides padded: 40*2=80 B (20 banks,
    // 2-way), 264*2=528 B (4-bank step, 2-way) -> conflict-free per m136.
    constexpr int SBYTES = (MODE == 2) ? 23520 : 50688;
    __shared__ __align__(16) char smem[SBYTES];
    __bf16 (*sX)[98][40] = (__bf16 (*)[98][40])smem;

    const int h    = blockIdx.x;        // output row
    const int img  = blockIdx.y;
    const int t    = threadIdx.x;
    const int wave = t >> 6;
    const int lane = t & 63;
    const int lq   = lane >> 4;         // quad 0..3
    const int lr   = lane & 15;
    const int mbase = wave * (MPW * 16);
    const int imgIn = img + imgInOfs;

    f32x4 acc[MPW][6];
#pragma unroll
    for (int mi = 0; mi < MPW; ++mi)
#pragma unroll
        for (int ni = 0; ni < 6; ++ni)
            acc[mi][ni] = (f32x4){0.f, 0.f, 0.f, 0.f};

    const int KC = Cin >> 5;   // K-chunks of 32 ci
    for (int kc = 0; kc < KC; ++kc) {
        __syncthreads();
        // ---- stage: 3 rows x 98 cols x 32 ci, channels-last bf16 ----------
        for (int base = t; base < 294; base += 256) {
            int r  = base / 98;
            int gw = base - r * 98;
            int gh = h - 1 + r;
            int gx = gw - 1;
            bool ok = ((unsigned)gh < 96u) && ((unsigned)gx < 96u);
            const float* src = X + ((size_t)gh * WW + gx);
            __bf16 tmp[32];
#pragma unroll
            for (int cc = 0; cc < 32; ++cc) {
                int ci = kc * 32 + cc;
                int plane = ((ci >> 6) << 8) + imgIn * 64 + (ci & 63);
                float v = ok ? src[(size_t)plane * HWSZ] : 0.f;
                tmp[cc] = (__bf16)v;
            }
            uint4* d = (uint4*)&sX[r][gw][0];
            const uint4* s = (const uint4*)tmp;
            d[0] = s[0]; d[1] = s[1]; d[2] = s[2]; d[3] = s[3];
        }
        __syncthreads();

        // ---- 9 tap-GEMMs over this K-chunk --------------------------------
        const __bf16* wbase = wT2 + ((size_t)(mbase + lr)) * Cin + kc * 32 + lq * 8;
#pragma unroll
        for (int tap = 0; tap < 9; ++tap) {
            const int ky = tap / 3, kx = tap - ky * 3;
            bf16x8 aF[MPW];
#pragma unroll
            for (int mi = 0; mi < MPW; ++mi)
                aF[mi] = *(const bf16x8*)(wbase +
                          ((size_t)tap * CmidPad + mi * 16) * Cin);
#pragma unroll
            for (int ni = 0; ni < 6; ++ni) {
                bf16x8 bF = *(const bf16x8*)&sX[ky][ni * 16 + lr + kx][lq * 8];
#pragma unroll
                for (int mi = 0; mi < MPW; ++mi)
                    acc[mi][ni] = __builtin_amdgcn_mfma_f32_16x16x32_bf16(
                        aF[mi], bF, acc[mi][ni], 0, 0, 0);
            }
        }
    }

    if (MODE == 2) {
        // raw conv + bias store (off conv); mask co >= Cf (189)
#pragma unroll
        for (int mi = 0; mi < MPW; ++mi)
#pragma unroll
            for (int ni = 0; ni < 6; ++ni) {
                int px = ni * 16 + lr;
#pragma unroll
                for (int r = 0; r < 4; ++r) {
                    int co = mbase + mi * 16 + lq * 4 + r;
                    if (co < Cf)
                        out[((size_t)(img * 189 + co)) * HWSZ + h * WW + px] =
                            acc[mi][ni][r] + b1[co];
                }
            }
        return;
    } else {
        // ---- hidden = relu(conv+b1) -> channels-last bf16 LDS -------------
        __syncthreads();   // done reading sX (overlay)
        __bf16 (*sH)[264] = (__bf16 (*)[264])smem;
#pragma unroll
        for (int mi = 0; mi < MPW; ++mi) {
            int co0 = mbase + mi * 16 + lq * 4;
            float bb0 = b1[co0], bb1 = b1[co0 + 1], bb2 = b1[co0 + 2], bb3 = b1[co0 + 3];
#pragma unroll
            for (int ni = 0; ni < 6; ++ni) {
                int px = ni * 16 + lr;
                bf16x4 hv;
                hv[0] = (__bf16)fmaxf(acc[mi][ni][0] + bb0, 0.f);
                hv[1] = (__bf16)fmaxf(acc[mi][ni][1] + bb1, 0.f);
                hv[2] = (__bf16)fmaxf(acc[mi][ni][2] + bb2, 0.f);
                hv[3] = (__bf16)fmaxf(acc[mi][ni][3] + bb3, 0.f);
                *(bf16x4*)&sH[px][co0] = hv;
            }
        }
        __syncthreads();

        // ---- 1x1 via MFMA: M=Cf, K=256, N=96 ------------------------------
        const int MT2 = (Cf + 15) >> 4;
        for (int tt = wave; tt < MT2 * 6; tt += 4) {
            int ni = tt / MT2;
            int mt = tt - ni * MT2;
            int cf = mt * 16 + lr; if (cf > Cf - 1) cf = Cf - 1;
            const __bf16* wrow = w2b + (size_t)cf * 256 + lq * 8;
            f32x4 c = (f32x4){0.f, 0.f, 0.f, 0.f};
#pragma unroll
            for (int kc = 0; kc < 8; ++kc) {
                bf16x8 aF = *(const bf16x8*)(wrow + kc * 32);
                bf16x8 bF = *(const bf16x8*)&sH[ni * 16 + lr][kc * 32 + lq * 8];
                c = __builtin_amdgcn_mfma_f32_16x16x32_bf16(aF, bF, c, 0, 0, 0);
            }
            int px = ni * 16 + lr;
#pragma unroll
            for (int r = 0; r < 4; ++r) {
                int cfr = mt * 16 + lq * 4 + r;
                if (cfr < Cf) {
                    int och;
                    if (MODE == 1) {
                        och = (img & 3) * 14 + (img >> 2) * 2 + cfr;
                    } else {
                        och = img * Cf + cfr;
                    }
                    out[(size_t)och * HWSZ + h * WW + px] = c[r] + b2[cfr];
                }
            }
        }
    }
}

// ---------------------------------------------------------------------------
// DCNv2 + bias + BN + ReLU + bz 1x1 conv, fused (fp32, unchanged from R1).
// ---------------------------------------------------------------------------
#define DTP 16
__global__ __launch_bounds__(256) void dcn_bz(
    const float* __restrict__ X,
    const float* __restrict__ offmap,
    const float* __restrict__ dwT,      // [(ci*9+k)*256 + co]
    const float* __restrict__ dcn_b,
    const float* __restrict__ bn_g, const float* __restrict__ bn_be,
    const float* __restrict__ bn_mn, const float* __restrict__ bn_vr,
    const float* __restrict__ bzw,
    const float* __restrict__ bzb,
    float* __restrict__ out_bz)
{
    __shared__ unsigned short sIdx[63 * DTP * 4];
    __shared__ float          sWt [63 * DTP * 4];
    __shared__ float          sV  [4][9][DTP];
    __shared__ __hip_bfloat16 sD  [256][DTP];

    const int b    = blockIdx.y;
    const int tile = blockIdx.x;
    const int h    = tile / 6;
    const int w0   = (tile % 6) * DTP;
    const int t    = threadIdx.x;

    const float* offp = offmap + (size_t)b * 189 * HWSZ;

    for (int e = t; e < 63 * DTP; e += 256) {
        int gk = e >> 4;
        int px = e & (DTP - 1);
        int k  = gk % 9;
        int pix = h * WW + w0 + px;
        float oy = offp[(size_t)gk * HWSZ + pix];
        float ox = offp[(size_t)(63 + gk) * HWSZ + pix];
        float mv = offp[(size_t)(126 + gk) * HWSZ + pix];
        float m  = 1.f / (1.f + expf(-mv));
        int ky = k / 3, kx = k - ky * 3;
        float sy = (float)(h - 1 + ky) + oy;
        float sx = (float)(w0 + px - 1 + kx) + ox;
        float fy = floorf(sy), fx = floorf(sx);
        float wy = sy - fy,    wx = sx - fx;
        int y0 = (int)fy, x0 = (int)fx;
        int y1 = y0 + 1,  x1 = x0 + 1;

        int base = e * 4;
        int   ys[4] = {y0, y0, y1, y1};
        int   xs[4] = {x0, x1, x0, x1};
        float ws4[4] = {(1.f - wy) * (1.f - wx), (1.f - wy) * wx,
                        wy * (1.f - wx),          wy * wx};
#pragma unroll
        for (int tp = 0; tp < 4; ++tp) {
            int yy = ys[tp], xx = xs[tp];
            bool valid = (yy >= 0) && (yy < HH) && (xx >= 0) && (xx < WW);
            int yc = min(max(yy, 0), HH - 1);
            int xc = min(max(xx, 0), WW - 1);
            sIdx[base + tp] = (unsigned short)(yc * WW + xc);
            sWt [base + tp] = valid ? ws4[tp] * m : 0.f;
        }
    }

    const int coA = t & 127;
    const int coB = coA + 128;
    const int pxh = (t >> 7) << 3;

    float acc0[8], acc1[8];
#pragma unroll
    for (int j = 0; j < 8; ++j) { acc0[j] = 0.f; acc1[j] = 0.f; }

    for (int g = 0; g < KF; ++g) {
        for (int c0 = 0; c0 < 64; c0 += 4) {
            __syncthreads();
            if (t < 144) {
                int k  = t >> 4;
                int px = t & 15;
                int e4 = ((g * 9 + k) * DTP + px) * 4;
                ushort4 i4 = *(const ushort4*)&sIdx[e4];
                float4  w4 = *(const float4*)&sWt[e4];
                const float* pl = X + ((size_t)((g * BB_ + b) * CC_ + c0)) * HWSZ;
#pragma unroll
                for (int cc = 0; cc < 4; ++cc) {
                    const float* p = pl + (size_t)cc * HWSZ;
                    sV[cc][k][px] = w4.x * p[i4.x] + w4.y * p[i4.y] +
                                    w4.z * p[i4.z] + w4.w * p[i4.w];
                }
            }
            __syncthreads();
            const float* wr0 = dwT + ((size_t)(g * 64 + c0)) * 9 * 256;
            for (int cc = 0; cc < 4; ++cc) {
                const float* wr = wr0 + (size_t)cc * 9 * 256;
#pragma unroll
                for (int k = 0; k < 9; ++k) {
                    float wA = wr[k * 256 + coA];
                    float wB = wr[k * 256 + coB];
                    const float4* vp = (const float4*)&sV[cc][k][pxh];
                    float4 va = vp[0];
                    float4 vb = vp[1];
                    acc0[0] = fmaf(wA, va.x, acc0[0]);
                    acc0[1] = fmaf(wA, va.y, acc0[1]);
                    acc0[2] = fmaf(wA, va.z, acc0[2]);
                    acc0[3] = fmaf(wA, va.w, acc0[3]);
                    acc0[4] = fmaf(wA, vb.x, acc0[4]);
                    acc0[5] = fmaf(wA, vb.y, acc0[5]);
                    acc0[6] = fmaf(wA, vb.z, acc0[6]);
                    acc0[7] = fmaf(wA, vb.w, acc0[7]);
                    acc1[0] = fmaf(wB, va.x, acc1[0]);
                    acc1[1] = fmaf(wB, va.y, acc1[1]);
                    acc1[2] = fmaf(wB, va.z, acc1[2]);
                    acc1[3] = fmaf(wB, va.w, acc1[3]);
                    acc1[4] = fmaf(wB, vb.x, acc1[4]);
                    acc1[5] = fmaf(wB, vb.y, acc1[5]);
                    acc1[6] = fmaf(wB, vb.z, acc1[6]);
                    acc1[7] = fmaf(wB, vb.w, acc1[7]);
                }
            }
        }
    }

    {
        float scA = bn_g[coA] * rsqrtf(bn_vr[coA] + 1e-5f);
        float scB = bn_g[coB] * rsqrtf(bn_vr[coB] + 1e-5f);
        float mA = bn_mn[coA], mB = bn_mn[coB];
        float eA = bn_be[coA], eB = bn_be[coB];
        float dA = dcn_b[coA], dB = dcn_b[coB];
#pragma unroll
        for (int j = 0; j < 8; ++j) {
            float v = (acc0[j] + dA - mA) * scA + eA;
            sD[coA][pxh + j] = __float2bfloat16(fmaxf(v, 0.f));
            float u = (acc1[j] + dB - mB) * scB + eB;
            sD[coB][pxh + j] = __float2bfloat16(fmaxf(u, 0.f));
        }
    }
    __syncthreads();

    {
        int cf = t >> 4;
        int px = t & 15;
        float s = bzb[cf];
        const float* wr = bzw + (size_t)cf * 256;
        for (int co = 0; co < 256; ++co)
            s = fmaf(wr[co], __bfloat162float(sD[co][px]), s);
        out_bz[((size_t)(b * 16 + cf)) * HWSZ + h * WW + w0 + px] = s;
    }
}

// ---------------------------------------------------------------------------
// Launch
// ---------------------------------------------------------------------------
extern "C" void kernel_launch(void* const* d_in, const int* in_sizes, int n_in,
                              void* d_out, int out_size, void* d_ws, size_t ws_size,
                              hipStream_t stream) {
    const float* feat   = (const float*)d_in[0];
    const float* hm_w1  = (const float*)d_in[1];
    const float* hm_b1  = (const float*)d_in[2];
    const float* hm_w2  = (const float*)d_in[3];
    const float* hm_b2  = (const float*)d_in[4];
    const float* wh_w1  = (const float*)d_in[5];
    const float* wh_b1  = (const float*)d_in[6];
    const float* wh_w2  = (const float*)d_in[7];
    const float* wh_b2  = (const float*)d_in[8];
    const float* id_w1  = (const float*)d_in[9];
    const float* id_b1  = (const float*)d_in[10];
    const float* id_w2  = (const float*)d_in[11];
    const float* id_b2  = (const float*)d_in[12];
    const float* off_w  = (const float*)d_in[13];
    const float* off_b  = (const float*)d_in[14];
    const float* dcn_w  = (const float*)d_in[15];
    const float* dcn_b  = (const float*)d_in[16];
    const float* bn_g   = (const float*)d_in[17];
    const float* bn_be  = (const float*)d_in[18];
    const float* bn_mn  = (const float*)d_in[19];
    const float* bn_vr  = (const float*)d_in[20];
    const float* bz_w   = (const float*)d_in[21];
    const float* bz_b   = (const float*)d_in[22];

    // Workspace layout
    float* ws      = (float*)d_ws;
    float* off_out = ws;                        // 6,967,296 f
    float* dcn_wT  = off_out + 6967296;         // 1,032,192 f
    __bf16* bfw    = (__bf16*)(dcn_wT + 1032192);
    __bf16* wh_wT2 = bfw;                       // 9*256*64  = 147,456
    __bf16* hm_wT2 = wh_wT2 + 147456;           //             147,456
    __bf16* id_wT2 = hm_wT2 + 147456;           // 9*256*448 = 1,032,192
    __bf16* off_wT2= id_wT2 + 1032192;          // 9*192*448 =   774,144
    __bf16* wh_w2b = off_wT2 + 774144;          //       512
    __bf16* hm_w2b = wh_w2b + 512;              //      6144
    __bf16* id_w2b = hm_w2b + 6144;             //     32768

    // Output layout (floats, concatenated): hm, bz, idout, owh
    float* out_hm = (float*)d_out;              // (4,24,96,96)
    float* out_bz = out_hm + 884736;            // (4,16,96,96)
    float* out_id = out_bz + 589824;            // (4,128,96,96)
    float* out_wh = out_id + 4718592;           // (4,14,96,96)

    // 1) weight prep
    cvt_taps<<<(147456 + 255) / 256, 256, 0, stream>>>(wh_w1, wh_wT2, 256, 64, 256);
    cvt_taps<<<(147456 + 255) / 256, 256, 0, stream>>>(hm_w1, hm_wT2, 256, 64, 256);
    cvt_taps<<<(1032192 + 255) / 256, 256, 0, stream>>>(id_w1, id_wT2, 256, 448, 256);
    cvt_taps<<<(762048 + 255) / 256, 256, 0, stream>>>(off_w, off_wT2, 189, 448, 192);
    cvt_flat<<<(512 + 255) / 256, 256, 0, stream>>>(wh_w2, wh_w2b, 512);
    cvt_flat<<<(6144 + 255) / 256, 256, 0, stream>>>(hm_w2, hm_w2b, 6144);
    cvt_flat<<<(32768 + 255) / 256, 256, 0, stream>>>(id_w2, id_w2b, 32768);
    transpose_w<<<(1032192 + 255) / 256, 256, 0, stream>>>(dcn_w, dcn_wT, 256, 448);

    // 2) MFMA conv branches (block = one row, grid = (96, n_images))
    conv3x3_mfma<4, 1><<<dim3(96, 28), 256, 0, stream>>>(
        feat, wh_wT2, wh_b1, wh_w2b, wh_b2, out_wh, 64, 256, 2, 0);
    conv3x3_mfma<4, 0><<<dim3(96, 4), 256, 0, stream>>>(
        feat, hm_wT2, hm_b1, hm_w2b, hm_b2, out_hm, 64, 256, 24, 12);
    conv3x3_mfma<4, 0><<<dim3(96, 4), 256, 0, stream>>>(
        feat, id_wT2, id_b1, id_w2b, id_b2, out_id, 448, 256, 128, 0);
    conv3x3_mfma<3, 2><<<dim3(96, 4), 256, 0, stream>>>(
        feat, off_wT2, off_b, nullptr, nullptr, off_out, 448, 192, 189, 0);

    // 3) DCN + BN + ReLU + bz (consumes off_out)
    dcn_bz<<<dim3(576, 4), 256, 0, stream>>>(
        feat, off_out, dcn_wT, dcn_b, bn_g, bn_be, bn_mn, bn_vr,
        bz_w, bz_b, out_bz);
}

// Round 3
// 2277.980 us; speedup vs baseline: 2.3239x; 1.4475x over previous
//
#include <hip/hip_runtime.h>
#include <hip/hip_bf16.h>
#include <math.h>

// Problem constants
#define KF   7      // frames / groups
#define BB_  4      // batch
#define CC_  64     // channels per frame
#define HH   96
#define WW   96
#define HWSZ 9216   // 96*96
#define HEAD 256

typedef __bf16 bf16x8 __attribute__((ext_vector_type(8)));
typedef __bf16 bf16x4 __attribute__((ext_vector_type(4)));
typedef float  f32x4  __attribute__((ext_vector_type(4)));

// ---------------------------------------------------------------------------
// Weight prep
// ---------------------------------------------------------------------------
// w[co][ci][k] fp32 -> wT2[(k*CoutPad + co)*Cin + ci] bf16 (ci contiguous)
__global__ __launch_bounds__(256) void cvt_taps(const float* __restrict__ w,
                                                __bf16* __restrict__ out,
                                                int Cout, int Cin, int CoutPad) {
    int e = blockIdx.x * 256 + threadIdx.x;
    int tot = Cout * Cin * 9;
    if (e >= tot) return;
    int co = e / (Cin * 9);
    int r  = e - co * (Cin * 9);
    int ci = r / 9;
    int k  = r - ci * 9;
    out[((size_t)k * CoutPad + co) * Cin + ci] = (__bf16)w[e];
}

// elementwise fp32 -> bf16 (same layout)
__global__ __launch_bounds__(256) void cvt_flat(const float* __restrict__ w,
                                                __bf16* __restrict__ out, int n) {
    int e = blockIdx.x * 256 + threadIdx.x;
    if (e < n) out[e] = (__bf16)w[e];
}

// DCN weights: dcn_w[o][g*64+c][ktap] -> wA[o*4032 + g*576 + ktap*64 + c] bf16
__global__ __launch_bounds__(256) void cvt_dcnA(const float* __restrict__ w,
                                                __bf16* __restrict__ out) {
    int e = blockIdx.x * 256 + threadIdx.x;
    if (e >= 256 * 4032) return;
    int co = e / 4032;
    int r  = e - co * 4032;
    int g  = r / 576;
    int r2 = r - g * 576;
    int tap = r2 >> 6;
    int c   = r2 & 63;
    out[e] = (__bf16)w[((size_t)co * 448 + g * 64 + c) * 9 + tap];
}

// ---------------------------------------------------------------------------
// MFMA conv3x3 (+bias,+relu) -> optional MFMA 1x1 (+bias).  (unchanged R2)
// ---------------------------------------------------------------------------
template<int MPW, int MODE>
__global__ __launch_bounds__(256) void conv3x3_mfma(
    const float* __restrict__ X,
    const __bf16* __restrict__ wT2,   // [(tap*CmidPad + co)*Cin + ci]
    const float* __restrict__ b1,
    const __bf16* __restrict__ w2b,   // [cf*256 + co]
    const float* __restrict__ b2,
    float* __restrict__ out,
    int Cin, int CmidPad, int Cf, int imgInOfs)
{
    constexpr int SBYTES = (MODE == 2) ? 23520 : 50688;
    __shared__ __align__(16) char smem[SBYTES];
    __bf16 (*sX)[98][40] = (__bf16 (*)[98][40])smem;

    const int h    = blockIdx.x;
    const int img  = blockIdx.y;
    const int t    = threadIdx.x;
    const int wave = t >> 6;
    const int lane = t & 63;
    const int lq   = lane >> 4;
    const int lr   = lane & 15;
    const int mbase = wave * (MPW * 16);
    const int imgIn = img + imgInOfs;

    f32x4 acc[MPW][6];
#pragma unroll
    for (int mi = 0; mi < MPW; ++mi)
#pragma unroll
        for (int ni = 0; ni < 6; ++ni)
            acc[mi][ni] = (f32x4){0.f, 0.f, 0.f, 0.f};

    const int KC = Cin >> 5;
    for (int kc = 0; kc < KC; ++kc) {
        __syncthreads();
        for (int base = t; base < 294; base += 256) {
            int r  = base / 98;
            int gw = base - r * 98;
            int gh = h - 1 + r;
            int gx = gw - 1;
            bool ok = ((unsigned)gh < 96u) && ((unsigned)gx < 96u);
            const float* src = X + ((size_t)gh * WW + gx);
            __bf16 tmp[32];
#pragma unroll
            for (int cc = 0; cc < 32; ++cc) {
                int ci = kc * 32 + cc;
                int plane = ((ci >> 6) << 8) + imgIn * 64 + (ci & 63);
                float v = ok ? src[(size_t)plane * HWSZ] : 0.f;
                tmp[cc] = (__bf16)v;
            }
            uint4* d = (uint4*)&sX[r][gw][0];
            const uint4* s = (const uint4*)tmp;
            d[0] = s[0]; d[1] = s[1]; d[2] = s[2]; d[3] = s[3];
        }
        __syncthreads();

        const __bf16* wbase = wT2 + ((size_t)(mbase + lr)) * Cin + kc * 32 + lq * 8;
#pragma unroll
        for (int tap = 0; tap < 9; ++tap) {
            const int ky = tap / 3, kx = tap - ky * 3;
            bf16x8 aF[MPW];
#pragma unroll
            for (int mi = 0; mi < MPW; ++mi)
                aF[mi] = *(const bf16x8*)(wbase +
                          ((size_t)tap * CmidPad + mi * 16) * Cin);
#pragma unroll
            for (int ni = 0; ni < 6; ++ni) {
                bf16x8 bF = *(const bf16x8*)&sX[ky][ni * 16 + lr + kx][lq * 8];
#pragma unroll
                for (int mi = 0; mi < MPW; ++mi)
                    acc[mi][ni] = __builtin_amdgcn_mfma_f32_16x16x32_bf16(
                        aF[mi], bF, acc[mi][ni], 0, 0, 0);
            }
        }
    }

    if (MODE == 2) {
#pragma unroll
        for (int mi = 0; mi < MPW; ++mi)
#pragma unroll
            for (int ni = 0; ni < 6; ++ni) {
                int px = ni * 16 + lr;
#pragma unroll
                for (int r = 0; r < 4; ++r) {
                    int co = mbase + mi * 16 + lq * 4 + r;
                    if (co < Cf)
                        out[((size_t)(img * 189 + co)) * HWSZ + h * WW + px] =
                            acc[mi][ni][r] + b1[co];
                }
            }
        return;
    } else {
        __syncthreads();
        __bf16 (*sH)[264] = (__bf16 (*)[264])smem;
#pragma unroll
        for (int mi = 0; mi < MPW; ++mi) {
            int co0 = mbase + mi * 16 + lq * 4;
            float bb0 = b1[co0], bb1 = b1[co0 + 1], bb2 = b1[co0 + 2], bb3 = b1[co0 + 3];
#pragma unroll
            for (int ni = 0; ni < 6; ++ni) {
                int px = ni * 16 + lr;
                bf16x4 hv;
                hv[0] = (__bf16)fmaxf(acc[mi][ni][0] + bb0, 0.f);
                hv[1] = (__bf16)fmaxf(acc[mi][ni][1] + bb1, 0.f);
                hv[2] = (__bf16)fmaxf(acc[mi][ni][2] + bb2, 0.f);
                hv[3] = (__bf16)fmaxf(acc[mi][ni][3] + bb3, 0.f);
                *(bf16x4*)&sH[px][co0] = hv;
            }
        }
        __syncthreads();

        const int MT2 = (Cf + 15) >> 4;
        for (int tt = wave; tt < MT2 * 6; tt += 4) {
            int ni = tt / MT2;
            int mt = tt - ni * MT2;
            int cf = mt * 16 + lr; if (cf > Cf - 1) cf = Cf - 1;
            const __bf16* wrow = w2b + (size_t)cf * 256 + lq * 8;
            f32x4 c = (f32x4){0.f, 0.f, 0.f, 0.f};
#pragma unroll
            for (int kc = 0; kc < 8; ++kc) {
                bf16x8 aF = *(const bf16x8*)(wrow + kc * 32);
                bf16x8 bF = *(const bf16x8*)&sH[ni * 16 + lr][kc * 32 + lq * 8];
                c = __builtin_amdgcn_mfma_f32_16x16x32_bf16(aF, bF, c, 0, 0, 0);
            }
            int px = ni * 16 + lr;
#pragma unroll
            for (int r = 0; r < 4; ++r) {
                int cfr = mt * 16 + lq * 4 + r;
                if (cfr < Cf) {
                    int och;
                    if (MODE == 1) {
                        och = (img & 3) * 14 + (img >> 2) * 2 + cfr;
                    } else {
                        och = img * Cf + cfr;
                    }
                    out[(size_t)och * HWSZ + h * WW + px] = c[r] + b2[cfr];
                }
            }
        }
    }
}

// ---------------------------------------------------------------------------
// DCNv2 via MFMA + bias + BN + ReLU + bz 1x1, fused.
// Block = (b, h, 48-px half-row). GEMM: out[256][48] = W[256][4032]*cols[4032][48],
// K-order (g, tap, c). cols built 3 taps (K=192) at a time in LDS bf16.
// Bilinear corners clamped to [0,94] with position-remapped weights (validity
// and sigmoid(mask) folded in) so all 4 corner loads are in-plane.
// ---------------------------------------------------------------------------
#define DNP 48
__global__ __launch_bounds__(256) void dcn_bz_mfma(
    const float* __restrict__ X,
    const float* __restrict__ offmap,   // (B,189,H,W)
    const __bf16* __restrict__ wA,      // [co][4032]
    const float* __restrict__ dcn_b,
    const float* __restrict__ bn_g, const float* __restrict__ bn_be,
    const float* __restrict__ bn_mn, const float* __restrict__ bn_vr,
    const __bf16* __restrict__ bzwb,    // [16][256]
    const float* __restrict__ bzb,
    float* __restrict__ out_bz)
{
    __shared__ __align__(16) char smem[30720];
    __bf16 (*sC)[DNP][40] = (__bf16 (*)[DNP][40])smem;   // [6][48][40] staging
    __bf16 (*sD)[DNP][40] = (__bf16 (*)[DNP][40])smem;   // [8][48][40] epilogue

    const int b    = blockIdx.y;
    const int h    = blockIdx.x >> 1;
    const int w0   = (blockIdx.x & 1) * DNP;
    const int t    = threadIdx.x;
    const int wave = t >> 6;
    const int lane = t & 63;
    const int lq   = lane >> 4;
    const int lr   = lane & 15;
    const int mbase = wave * 64;

    const float* offp = offmap + (size_t)b * 189 * HWSZ;

    f32x4 acc[4][3];
#pragma unroll
    for (int mi = 0; mi < 4; ++mi)
#pragma unroll
        for (int ni = 0; ni < 3; ++ni)
            acc[mi][ni] = (f32x4){0.f, 0.f, 0.f, 0.f};

    for (int g = 0; g < KF; ++g) {
        const float* Xg = X + ((size_t)(g * BB_ + b) * CC_) * HWSZ;
        for (int c3 = 0; c3 < 3; ++c3) {
            __syncthreads();
            // ---- build cols tile: taps [c3*3, c3*3+3), all 64 ci ----------
            for (int j = t; j < 288; j += 256) {
                int half = j / 144;          // ci half: 0 -> ci 0..31, 1 -> 32..63
                int p    = j - half * 144;
                int tl   = p / DNP;          // tap_local 0..2
                int px   = p - tl * DNP;
                int tap  = c3 * 3 + tl;
                int gk   = g * 9 + tap;
                int pix  = h * WW + w0 + px;
                float oy = offp[(size_t)gk * HWSZ + pix];
                float ox = offp[(size_t)(63 + gk) * HWSZ + pix];
                float mv = offp[(size_t)(126 + gk) * HWSZ + pix];
                float m  = 1.f / (1.f + expf(-mv));
                int ky = tap / 3, kx = tap - ky * 3;
                float sy = (float)(h - 1 + ky) + oy;
                float sx = (float)(w0 + px - 1 + kx) + ox;
                float fy = floorf(sy), fx = floorf(sx);
                float wy = sy - fy,    wx = sx - fx;
                int y0 = (int)fy, x0 = (int)fx;
                int by = min(max(y0, 0), 94);
                int bx = min(max(x0, 0), 94);
                // weight for loaded position {b,b+1}: remap true corners,
                // zero if the true corner is out of range
                float wy0 = (y0 == by ? 1.f - wy : 0.f) + (y0 + 1 == by ? wy : 0.f);
                float wy1 = (y0 == by + 1 ? 1.f - wy : 0.f) + (y0 + 1 == by + 1 ? wy : 0.f);
                float wx0 = (x0 == bx ? 1.f - wx : 0.f) + (x0 + 1 == bx ? wx : 0.f);
                float wx1 = (x0 == bx + 1 ? 1.f - wx : 0.f) + (x0 + 1 == bx + 1 ? wx : 0.f);
                float w00 = m * wy0 * wx0, w01 = m * wy0 * wx1;
                float w10 = m * wy1 * wx0, w11 = m * wy1 * wx1;
                int r0 = by * WW + bx;
                const float* pl = Xg + (size_t)(half * 32) * HWSZ + r0;
                int kcDst = tl * 2 + half;
                for (int c8 = 0; c8 < 4; ++c8) {
                    __bf16 tmp[8];
#pragma unroll
                    for (int i = 0; i < 8; ++i) {
                        const float* p2 = pl + (size_t)(c8 * 8 + i) * HWSZ;
                        float v = w00 * p2[0] + w01 * p2[1] +
                                  w10 * p2[WW] + w11 * p2[WW + 1];
                        tmp[i] = (__bf16)v;
                    }
                    *(uint4*)&sC[kcDst][px][c8 * 8] = *(const uint4*)tmp;
                }
            }
            __syncthreads();
            // ---- GEMM over this K=192 chunk (6 sub-chunks of 32) ----------
            const __bf16* wbase = wA + (size_t)(mbase + lr) * 4032 +
                                  (g * 18 + c3 * 6) * 32 + lq * 8;
#pragma unroll
            for (int kc = 0; kc < 6; ++kc) {
                bf16x8 aF[4];
#pragma unroll
                for (int mi = 0; mi < 4; ++mi)
                    aF[mi] = *(const bf16x8*)(wbase + (size_t)mi * 16 * 4032 + kc * 32);
#pragma unroll
                for (int ni = 0; ni < 3; ++ni) {
                    bf16x8 bF = *(const bf16x8*)&sC[kc][ni * 16 + lr][lq * 8];
#pragma unroll
                    for (int mi = 0; mi < 4; ++mi)
                        acc[mi][ni] = __builtin_amdgcn_mfma_f32_16x16x32_bf16(
                            aF[mi], bF, acc[mi][ni], 0, 0, 0);
                }
            }
        }
    }

    // ---- epilogue: bias + BN + relu -> channels-last bf16 LDS -------------
    __syncthreads();
#pragma unroll
    for (int mi = 0; mi < 4; ++mi) {
        int co0 = mbase + mi * 16 + lq * 4;
        float sc[4], sh[4];
#pragma unroll
        for (int r = 0; r < 4; ++r) {
            float s = bn_g[co0 + r] * rsqrtf(bn_vr[co0 + r] + 1e-5f);
            sc[r] = s;
            sh[r] = (dcn_b[co0 + r] - bn_mn[co0 + r]) * s + bn_be[co0 + r];
        }
#pragma unroll
        for (int ni = 0; ni < 3; ++ni) {
            int px = ni * 16 + lr;
            bf16x4 hv;
#pragma unroll
            for (int r = 0; r < 4; ++r)
                hv[r] = (__bf16)fmaxf(acc[mi][ni][r] * sc[r] + sh[r], 0.f);
            *(bf16x4*)&sD[co0 >> 5][px][co0 & 31] = hv;
        }
    }
    __syncthreads();

    // ---- bz 1x1: M=16, K=256, N=48 (3 n-tiles on waves 0..2) --------------
    if (wave < 3) {
        int ni = wave;
        const __bf16* wrow = bzwb + (size_t)lr * 256 + lq * 8;
        f32x4 c = (f32x4){0.f, 0.f, 0.f, 0.f};
#pragma unroll
        for (int kc = 0; kc < 8; ++kc) {
            bf16x8 aF = *(const bf16x8*)(wrow + kc * 32);
            bf16x8 bF = *(const bf16x8*)&sD[kc][ni * 16 + lr][lq * 8];
            c = __builtin_amdgcn_mfma_f32_16x16x32_bf16(aF, bF, c, 0, 0, 0);
        }
        int px = ni * 16 + lr;
#pragma unroll
        for (int r = 0; r < 4; ++r) {
            int cf = lq * 4 + r;
            out_bz[((size_t)(b * 16 + cf)) * HWSZ + h * WW + w0 + px] = c[r] + bzb[cf];
        }
    }
}

// ---------------------------------------------------------------------------
// Launch
// ---------------------------------------------------------------------------
extern "C" void kernel_launch(void* const* d_in, const int* in_sizes, int n_in,
                              void* d_out, int out_size, void* d_ws, size_t ws_size,
                              hipStream_t stream) {
    const float* feat   = (const float*)d_in[0];
    const float* hm_w1  = (const float*)d_in[1];
    const float* hm_b1  = (const float*)d_in[2];
    const float* hm_w2  = (const float*)d_in[3];
    const float* hm_b2  = (const float*)d_in[4];
    const float* wh_w1  = (const float*)d_in[5];
    const float* wh_b1  = (const float*)d_in[6];
    const float* wh_w2  = (const float*)d_in[7];
    const float* wh_b2  = (const float*)d_in[8];
    const float* id_w1  = (const float*)d_in[9];
    const float* id_b1  = (const float*)d_in[10];
    const float* id_w2  = (const float*)d_in[11];
    const float* id_b2  = (const float*)d_in[12];
    const float* off_w  = (const float*)d_in[13];
    const float* off_b  = (const float*)d_in[14];
    const float* dcn_w  = (const float*)d_in[15];
    const float* dcn_b  = (const float*)d_in[16];
    const float* bn_g   = (const float*)d_in[17];
    const float* bn_be  = (const float*)d_in[18];
    const float* bn_mn  = (const float*)d_in[19];
    const float* bn_vr  = (const float*)d_in[20];
    const float* bz_w   = (const float*)d_in[21];
    const float* bz_b   = (const float*)d_in[22];

    // Workspace layout
    float* ws      = (float*)d_ws;
    float* off_out = ws;                        // 6,967,296 f
    __bf16* bfw    = (__bf16*)(off_out + 6967296);
    __bf16* wh_wT2 = bfw;                       // 147,456
    __bf16* hm_wT2 = wh_wT2 + 147456;           // 147,456
    __bf16* id_wT2 = hm_wT2 + 147456;           // 1,032,192
    __bf16* off_wT2= id_wT2 + 1032192;          // 9*192*448 = 774,144
    __bf16* wh_w2b = off_wT2 + 774144;          //     512
    __bf16* hm_w2b = wh_w2b + 512;              //    6144
    __bf16* id_w2b = hm_w2b + 6144;             //   32768
    __bf16* dcn_wA = id_w2b + 32768;            // 256*4032 = 1,032,192
    __bf16* bz_wb  = dcn_wA + 1032192;          //    4096

    // Output layout (floats, concatenated): hm, bz, idout, owh
    float* out_hm = (float*)d_out;              // (4,24,96,96)
    float* out_bz = out_hm + 884736;            // (4,16,96,96)
    float* out_id = out_bz + 589824;            // (4,128,96,96)
    float* out_wh = out_id + 4718592;           // (4,14,96,96)

    // 1) weight prep
    cvt_taps<<<(147456 + 255) / 256, 256, 0, stream>>>(wh_w1, wh_wT2, 256, 64, 256);
    cvt_taps<<<(147456 + 255) / 256, 256, 0, stream>>>(hm_w1, hm_wT2, 256, 64, 256);
    cvt_taps<<<(1032192 + 255) / 256, 256, 0, stream>>>(id_w1, id_wT2, 256, 448, 256);
    cvt_taps<<<(762048 + 255) / 256, 256, 0, stream>>>(off_w, off_wT2, 189, 448, 192);
    cvt_flat<<<(512 + 255) / 256, 256, 0, stream>>>(wh_w2, wh_w2b, 512);
    cvt_flat<<<(6144 + 255) / 256, 256, 0, stream>>>(hm_w2, hm_w2b, 6144);
    cvt_flat<<<(32768 + 255) / 256, 256, 0, stream>>>(id_w2, id_w2b, 32768);
    cvt_flat<<<(4096 + 255) / 256, 256, 0, stream>>>(bz_w, bz_wb, 4096);
    cvt_dcnA<<<(1032192 + 255) / 256, 256, 0, stream>>>(dcn_w, dcn_wA);

    // 2) MFMA conv branches
    conv3x3_mfma<4, 1><<<dim3(96, 28), 256, 0, stream>>>(
        feat, wh_wT2, wh_b1, wh_w2b, wh_b2, out_wh, 64, 256, 2, 0);
    conv3x3_mfma<4, 0><<<dim3(96, 4), 256, 0, stream>>>(
        feat, hm_wT2, hm_b1, hm_w2b, hm_b2, out_hm, 64, 256, 24, 12);
    conv3x3_mfma<4, 0><<<dim3(96, 4), 256, 0, stream>>>(
        feat, id_wT2, id_b1, id_w2b, id_b2, out_id, 448, 256, 128, 0);
    conv3x3_mfma<3, 2><<<dim3(96, 4), 256, 0, stream>>>(
        feat, off_wT2, off_b, nullptr, nullptr, off_out, 448, 192, 189, 0);

    // 3) DCN via MFMA + BN + ReLU + bz (consumes off_out)
    dcn_bz_mfma<<<dim3(192, 4), 256, 0, stream>>>(
        feat, off_out, dcn_wA, dcn_b, bn_g, bn_be, bn_mn, bn_vr,
        bz_wb, bz_b, out_bz);
}

// Round 4
// 917.691 us; speedup vs baseline: 5.7685x; 2.4823x over previous
//
#include <hip/hip_runtime.h>
#include <hip/hip_bf16.h>
#include <math.h>

// Problem constants
#define KF   7      // frames / groups
#define BB_  4      // batch
#define CC_  64     // channels per frame
#define HH   96
#define WW   96
#define HWSZ 9216   // 96*96
#define HEAD 256
#define CH2  448    // channels-last width of X2

typedef __bf16 bf16x8 __attribute__((ext_vector_type(8)));
typedef __bf16 bf16x4 __attribute__((ext_vector_type(4)));
typedef float  f32x4  __attribute__((ext_vector_type(4)));

// ---------------------------------------------------------------------------
// features (K,B,C,H,W) fp32 -> X2[b][h][w][g*64+c] bf16 (channels-last)
// Block = one (g,b,h) row. LDS transpose for coalesced read AND write.
// ---------------------------------------------------------------------------
__global__ __launch_bounds__(256) void cvt_feat(const float* __restrict__ feat,
                                                __bf16* __restrict__ X2) {
    __shared__ float sT[96][65];
    const int h = blockIdx.x;
    const int n = blockIdx.y;          // g*4+b
    const int g = n >> 2, b = n & 3;
    const int t = threadIdx.x;
    const float* src = feat + (size_t)n * 64 * HWSZ + h * WW;
    for (int e = t; e < 6144; e += 256) {
        int c = e / 96, w = e - c * 96;
        sT[w][c] = src[(size_t)c * HWSZ + w];
    }
    __syncthreads();
    for (int u = t; u < 768; u += 256) {     // unit = 8 channels of one w
        int w = u >> 3, c8 = (u & 7) * 8;
        __bf16 tmp[8];
#pragma unroll
        for (int i = 0; i < 8; ++i) tmp[i] = (__bf16)sT[w][c8 + i];
        *(uint4*)&X2[(((size_t)(b * 96 + h)) * 96 + w) * CH2 + g * 64 + c8] =
            *(const uint4*)tmp;
    }
}

// ---------------------------------------------------------------------------
// Weight prep (unchanged)
// ---------------------------------------------------------------------------
__global__ __launch_bounds__(256) void cvt_taps(const float* __restrict__ w,
                                                __bf16* __restrict__ out,
                                                int Cout, int Cin, int CoutPad) {
    int e = blockIdx.x * 256 + threadIdx.x;
    int tot = Cout * Cin * 9;
    if (e >= tot) return;
    int co = e / (Cin * 9);
    int r  = e - co * (Cin * 9);
    int ci = r / 9;
    int k  = r - ci * 9;
    out[((size_t)k * CoutPad + co) * Cin + ci] = (__bf16)w[e];
}

__global__ __launch_bounds__(256) void cvt_flat(const float* __restrict__ w,
                                                __bf16* __restrict__ out, int n) {
    int e = blockIdx.x * 256 + threadIdx.x;
    if (e < n) out[e] = (__bf16)w[e];
}

// DCN weights: dcn_w[o][g*64+c][ktap] -> wA[o*4032 + g*576 + ktap*64 + c] bf16
__global__ __launch_bounds__(256) void cvt_dcnA(const float* __restrict__ w,
                                                __bf16* __restrict__ out) {
    int e = blockIdx.x * 256 + threadIdx.x;
    if (e >= 256 * 4032) return;
    int co = e / 4032;
    int r  = e - co * 4032;
    int g  = r / 576;
    int r2 = r - g * 576;
    int tap = r2 >> 6;
    int c   = r2 & 63;
    out[e] = (__bf16)w[((size_t)co * 448 + g * 64 + c) * 9 + tap];
}

// ---------------------------------------------------------------------------
// MFMA conv3x3 (+bias,+relu) -> optional MFMA 1x1 (+bias).
// Staging now reads channels-last bf16 X2 with uint4 loads (no conversion).
// whMap: 1 -> b=img&3, chanBase=(img>>2)*64 (wh); 0 -> b=img, chanBase arg.
// ---------------------------------------------------------------------------
template<int MPW, int MODE>
__global__ __launch_bounds__(256) void conv3x3_mfma(
    const __bf16* __restrict__ X2,
    const __bf16* __restrict__ wT2,   // [(tap*CmidPad + co)*Cin + ci]
    const float* __restrict__ b1,
    const __bf16* __restrict__ w2b,   // [cf*256 + co]
    const float* __restrict__ b2,
    float* __restrict__ out,
    int Cin, int CmidPad, int Cf, int chanBase, int whMap)
{
    constexpr int SBYTES = (MODE == 2) ? 23520 : 50688;
    __shared__ __align__(16) char smem[SBYTES];
    __bf16 (*sX)[98][40] = (__bf16 (*)[98][40])smem;

    const int h    = blockIdx.x;
    const int img  = blockIdx.y;
    const int t    = threadIdx.x;
    const int wave = t >> 6;
    const int lane = t & 63;
    const int lq   = lane >> 4;
    const int lr   = lane & 15;
    const int mbase = wave * (MPW * 16);

    const int bImg = whMap ? (img & 3) : img;
    const int cb   = whMap ? ((img >> 2) * 64) : chanBase;
    const __bf16* Xrow = X2 + ((size_t)bImg * 96) * 96 * CH2;

    f32x4 acc[MPW][6];
#pragma unroll
    for (int mi = 0; mi < MPW; ++mi)
#pragma unroll
        for (int ni = 0; ni < 6; ++ni)
            acc[mi][ni] = (f32x4){0.f, 0.f, 0.f, 0.f};

    const int KC = Cin >> 5;
    for (int kc = 0; kc < KC; ++kc) {
        __syncthreads();
        // ---- stage: 294 positions x 32ch (64 B each) via uint4 ------------
        for (int u = t; u < 1176; u += 256) {
            int pos = u >> 2;
            int q   = u & 3;
            int r   = pos / 98;
            int gw  = pos - r * 98;
            int gh  = h - 1 + r;
            int gx  = gw - 1;
            uint4 v = {0u, 0u, 0u, 0u};
            if (((unsigned)gh < 96u) && ((unsigned)gx < 96u))
                v = *(const uint4*)&Xrow[((size_t)gh * 96 + gx) * CH2 +
                                         cb + kc * 32 + q * 8];
            *(uint4*)&sX[r][gw][q * 8] = v;
        }
        __syncthreads();

        const __bf16* wbase = wT2 + ((size_t)(mbase + lr)) * Cin + kc * 32 + lq * 8;
#pragma unroll
        for (int tap = 0; tap < 9; ++tap) {
            const int ky = tap / 3, kx = tap - ky * 3;
            bf16x8 aF[MPW];
#pragma unroll
            for (int mi = 0; mi < MPW; ++mi)
                aF[mi] = *(const bf16x8*)(wbase +
                          ((size_t)tap * CmidPad + mi * 16) * Cin);
#pragma unroll
            for (int ni = 0; ni < 6; ++ni) {
                bf16x8 bF = *(const bf16x8*)&sX[ky][ni * 16 + lr + kx][lq * 8];
#pragma unroll
                for (int mi = 0; mi < MPW; ++mi)
                    acc[mi][ni] = __builtin_amdgcn_mfma_f32_16x16x32_bf16(
                        aF[mi], bF, acc[mi][ni], 0, 0, 0);
            }
        }
    }

    if (MODE == 2) {
#pragma unroll
        for (int mi = 0; mi < MPW; ++mi)
#pragma unroll
            for (int ni = 0; ni < 6; ++ni) {
                int px = ni * 16 + lr;
#pragma unroll
                for (int r = 0; r < 4; ++r) {
                    int co = mbase + mi * 16 + lq * 4 + r;
                    if (co < Cf)
                        out[((size_t)(img * 189 + co)) * HWSZ + h * WW + px] =
                            acc[mi][ni][r] + b1[co];
                }
            }
        return;
    } else {
        __syncthreads();
        __bf16 (*sH)[264] = (__bf16 (*)[264])smem;
#pragma unroll
        for (int mi = 0; mi < MPW; ++mi) {
            int co0 = mbase + mi * 16 + lq * 4;
            float bb0 = b1[co0], bb1 = b1[co0 + 1], bb2 = b1[co0 + 2], bb3 = b1[co0 + 3];
#pragma unroll
            for (int ni = 0; ni < 6; ++ni) {
                int px = ni * 16 + lr;
                bf16x4 hv;
                hv[0] = (__bf16)fmaxf(acc[mi][ni][0] + bb0, 0.f);
                hv[1] = (__bf16)fmaxf(acc[mi][ni][1] + bb1, 0.f);
                hv[2] = (__bf16)fmaxf(acc[mi][ni][2] + bb2, 0.f);
                hv[3] = (__bf16)fmaxf(acc[mi][ni][3] + bb3, 0.f);
                *(bf16x4*)&sH[px][co0] = hv;
            }
        }
        __syncthreads();

        const int MT2 = (Cf + 15) >> 4;
        for (int tt = wave; tt < MT2 * 6; tt += 4) {
            int ni = tt / MT2;
            int mt = tt - ni * MT2;
            int cf = mt * 16 + lr; if (cf > Cf - 1) cf = Cf - 1;
            const __bf16* wrow = w2b + (size_t)cf * 256 + lq * 8;
            f32x4 c = (f32x4){0.f, 0.f, 0.f, 0.f};
#pragma unroll
            for (int kc = 0; kc < 8; ++kc) {
                bf16x8 aF = *(const bf16x8*)(wrow + kc * 32);
                bf16x8 bF = *(const bf16x8*)&sH[ni * 16 + lr][kc * 32 + lq * 8];
                c = __builtin_amdgcn_mfma_f32_16x16x32_bf16(aF, bF, c, 0, 0, 0);
            }
            int px = ni * 16 + lr;
#pragma unroll
            for (int r = 0; r < 4; ++r) {
                int cfr = mt * 16 + lq * 4 + r;
                if (cfr < Cf) {
                    int och;
                    if (MODE == 1) {
                        och = (img & 3) * 14 + (img >> 2) * 2 + cfr;
                    } else {
                        och = img * Cf + cfr;
                    }
                    out[(size_t)och * HWSZ + h * WW + px] = c[r] + b2[cfr];
                }
            }
        }
    }
}

// ---------------------------------------------------------------------------
// DCNv2 via MFMA + bias + BN + ReLU + bz 1x1, fused.
// Gather now reads X2 (channels-last bf16) with bf16x8 corner loads.
// ---------------------------------------------------------------------------
#define DNP 48
__global__ __launch_bounds__(256) void dcn_bz_mfma(
    const __bf16* __restrict__ X2,
    const float* __restrict__ offmap,   // (B,189,H,W) fp32
    const __bf16* __restrict__ wA,      // [co][4032]
    const float* __restrict__ dcn_b,
    const float* __restrict__ bn_g, const float* __restrict__ bn_be,
    const float* __restrict__ bn_mn, const float* __restrict__ bn_vr,
    const __bf16* __restrict__ bzwb,    // [16][256]
    const float* __restrict__ bzb,
    float* __restrict__ out_bz)
{
    __shared__ __align__(16) char smem[30720];
    __bf16 (*sC)[DNP][40] = (__bf16 (*)[DNP][40])smem;   // [6][48][40] staging
    __bf16 (*sD)[DNP][40] = (__bf16 (*)[DNP][40])smem;   // [8][48][40] epilogue

    const int b    = blockIdx.y;
    const int h    = blockIdx.x >> 1;
    const int w0   = (blockIdx.x & 1) * DNP;
    const int t    = threadIdx.x;
    const int wave = t >> 6;
    const int lane = t & 63;
    const int lq   = lane >> 4;
    const int lr   = lane & 15;
    const int mbase = wave * 64;

    const float* offp = offmap + (size_t)b * 189 * HWSZ;
    const __bf16* Xb  = X2 + ((size_t)b * 96) * 96 * CH2;

    f32x4 acc[4][3];
#pragma unroll
    for (int mi = 0; mi < 4; ++mi)
#pragma unroll
        for (int ni = 0; ni < 3; ++ni)
            acc[mi][ni] = (f32x4){0.f, 0.f, 0.f, 0.f};

    for (int g = 0; g < KF; ++g) {
        for (int c3 = 0; c3 < 3; ++c3) {
            __syncthreads();
            // ---- build cols tile: taps [c3*3, c3*3+3), all 64 ci ----------
            for (int j = t; j < 288; j += 256) {
                int half = j / 144;          // ci half: 0 -> 0..31, 1 -> 32..63
                int p    = j - half * 144;
                int tl   = p / DNP;          // tap_local 0..2
                int px   = p - tl * DNP;
                int tap  = c3 * 3 + tl;
                int gk   = g * 9 + tap;
                int pix  = h * WW + w0 + px;
                float oy = offp[(size_t)gk * HWSZ + pix];
                float ox = offp[(size_t)(63 + gk) * HWSZ + pix];
                float mv = offp[(size_t)(126 + gk) * HWSZ + pix];
                float m  = 1.f / (1.f + expf(-mv));
                int ky = tap / 3, kx = tap - ky * 3;
                float sy = (float)(h - 1 + ky) + oy;
                float sx = (float)(w0 + px - 1 + kx) + ox;
                float fy = floorf(sy), fx = floorf(sx);
                float wy = sy - fy,    wx = sx - fx;
                int y0 = (int)fy, x0 = (int)fx;
                int by = min(max(y0, 0), 94);
                int bx = min(max(x0, 0), 94);
                float wy0 = (y0 == by ? 1.f - wy : 0.f) + (y0 + 1 == by ? wy : 0.f);
                float wy1 = (y0 == by + 1 ? 1.f - wy : 0.f) + (y0 + 1 == by + 1 ? wy : 0.f);
                float wx0 = (x0 == bx ? 1.f - wx : 0.f) + (x0 + 1 == bx ? wx : 0.f);
                float wx1 = (x0 == bx + 1 ? 1.f - wx : 0.f) + (x0 + 1 == bx + 1 ? wx : 0.f);
                float w00 = m * wy0 * wx0, w01 = m * wy0 * wx1;
                float w10 = m * wy1 * wx0, w11 = m * wy1 * wx1;
                const __bf16* pl = Xb + ((size_t)by * 96 + bx) * CH2 +
                                   g * 64 + half * 32;
                int kcDst = tl * 2 + half;
#pragma unroll
                for (int c8 = 0; c8 < 4; ++c8) {
                    bf16x8 c00 = *(const bf16x8*)(pl + c8 * 8);
                    bf16x8 c01 = *(const bf16x8*)(pl + CH2 + c8 * 8);
                    bf16x8 c10 = *(const bf16x8*)(pl + 96 * CH2 + c8 * 8);
                    bf16x8 c11 = *(const bf16x8*)(pl + 97 * CH2 + c8 * 8);
                    __bf16 tmp[8];
#pragma unroll
                    for (int i = 0; i < 8; ++i) {
                        float v = w00 * (float)c00[i] + w01 * (float)c01[i] +
                                  w10 * (float)c10[i] + w11 * (float)c11[i];
                        tmp[i] = (__bf16)v;
                    }
                    *(uint4*)&sC[kcDst][px][c8 * 8] = *(const uint4*)tmp;
                }
            }
            __syncthreads();
            // ---- GEMM over this K=192 chunk (6 sub-chunks of 32) ----------
            const __bf16* wbase = wA + (size_t)(mbase + lr) * 4032 +
                                  (g * 18 + c3 * 6) * 32 + lq * 8;
#pragma unroll
            for (int kc = 0; kc < 6; ++kc) {
                bf16x8 aF[4];
#pragma unroll
                for (int mi = 0; mi < 4; ++mi)
                    aF[mi] = *(const bf16x8*)(wbase + (size_t)mi * 16 * 4032 + kc * 32);
#pragma unroll
                for (int ni = 0; ni < 3; ++ni) {
                    bf16x8 bF = *(const bf16x8*)&sC[kc][ni * 16 + lr][lq * 8];
#pragma unroll
                    for (int mi = 0; mi < 4; ++mi)
                        acc[mi][ni] = __builtin_amdgcn_mfma_f32_16x16x32_bf16(
                            aF[mi], bF, acc[mi][ni], 0, 0, 0);
                }
            }
        }
    }

    // ---- epilogue: bias + BN + relu -> channels-last bf16 LDS -------------
    __syncthreads();
#pragma unroll
    for (int mi = 0; mi < 4; ++mi) {
        int co0 = mbase + mi * 16 + lq * 4;
        float sc[4], sh[4];
#pragma unroll
        for (int r = 0; r < 4; ++r) {
            float s = bn_g[co0 + r] * rsqrtf(bn_vr[co0 + r] + 1e-5f);
            sc[r] = s;
            sh[r] = (dcn_b[co0 + r] - bn_mn[co0 + r]) * s + bn_be[co0 + r];
        }
#pragma unroll
        for (int ni = 0; ni < 3; ++ni) {
            int px = ni * 16 + lr;
            bf16x4 hv;
#pragma unroll
            for (int r = 0; r < 4; ++r)
                hv[r] = (__bf16)fmaxf(acc[mi][ni][r] * sc[r] + sh[r], 0.f);
            *(bf16x4*)&sD[co0 >> 5][px][co0 & 31] = hv;
        }
    }
    __syncthreads();

    // ---- bz 1x1: M=16, K=256, N=48 (3 n-tiles on waves 0..2) --------------
    if (wave < 3) {
        int ni = wave;
        const __bf16* wrow = bzwb + (size_t)lr * 256 + lq * 8;
        f32x4 c = (f32x4){0.f, 0.f, 0.f, 0.f};
#pragma unroll
        for (int kc = 0; kc < 8; ++kc) {
            bf16x8 aF = *(const bf16x8*)(wrow + kc * 32);
            bf16x8 bF = *(const bf16x8*)&sD[kc][ni * 16 + lr][lq * 8];
            c = __builtin_amdgcn_mfma_f32_16x16x32_bf16(aF, bF, c, 0, 0, 0);
        }
        int px = ni * 16 + lr;
#pragma unroll
        for (int r = 0; r < 4; ++r) {
            int cf = lq * 4 + r;
            out_bz[((size_t)(b * 16 + cf)) * HWSZ + h * WW + w0 + px] = c[r] + bzb[cf];
        }
    }
}

// ---------------------------------------------------------------------------
// Launch
// ---------------------------------------------------------------------------
extern "C" void kernel_launch(void* const* d_in, const int* in_sizes, int n_in,
                              void* d_out, int out_size, void* d_ws, size_t ws_size,
                              hipStream_t stream) {
    const float* feat   = (const float*)d_in[0];
    const float* hm_w1  = (const float*)d_in[1];
    const float* hm_b1  = (const float*)d_in[2];
    const float* hm_w2  = (const float*)d_in[3];
    const float* hm_b2  = (const float*)d_in[4];
    const float* wh_w1  = (const float*)d_in[5];
    const float* wh_b1  = (const float*)d_in[6];
    const float* wh_w2  = (const float*)d_in[7];
    const float* wh_b2  = (const float*)d_in[8];
    const float* id_w1  = (const float*)d_in[9];
    const float* id_b1  = (const float*)d_in[10];
    const float* id_w2  = (const float*)d_in[11];
    const float* id_b2  = (const float*)d_in[12];
    const float* off_w  = (const float*)d_in[13];
    const float* off_b  = (const float*)d_in[14];
    const float* dcn_w  = (const float*)d_in[15];
    const float* dcn_b  = (const float*)d_in[16];
    const float* bn_g   = (const float*)d_in[17];
    const float* bn_be  = (const float*)d_in[18];
    const float* bn_mn  = (const float*)d_in[19];
    const float* bn_vr  = (const float*)d_in[20];
    const float* bz_w   = (const float*)d_in[21];
    const float* bz_b   = (const float*)d_in[22];

    // Workspace layout
    float* ws      = (float*)d_ws;
    float* off_out = ws;                        // 6,967,296 f (27.9 MB)
    __bf16* X2     = (__bf16*)(off_out + 6967296); // 4*96*96*448 = 16,515,072 bf16
    __bf16* bfw    = X2 + 16515072;
    __bf16* wh_wT2 = bfw;                       // 147,456
    __bf16* hm_wT2 = wh_wT2 + 147456;           // 147,456
    __bf16* id_wT2 = hm_wT2 + 147456;           // 1,032,192
    __bf16* off_wT2= id_wT2 + 1032192;          // 774,144
    __bf16* wh_w2b = off_wT2 + 774144;          //     512
    __bf16* hm_w2b = wh_w2b + 512;              //    6144
    __bf16* id_w2b = hm_w2b + 6144;             //   32768
    __bf16* dcn_wA = id_w2b + 32768;            // 1,032,192
    __bf16* bz_wb  = dcn_wA + 1032192;          //    4096

    // Output layout (floats, concatenated): hm, bz, idout, owh
    float* out_hm = (float*)d_out;              // (4,24,96,96)
    float* out_bz = out_hm + 884736;            // (4,16,96,96)
    float* out_id = out_bz + 589824;            // (4,128,96,96)
    float* out_wh = out_id + 4718592;           // (4,14,96,96)

    // 1) data + weight prep
    cvt_feat<<<dim3(96, 28), 256, 0, stream>>>(feat, X2);
    cvt_taps<<<(147456 + 255) / 256, 256, 0, stream>>>(wh_w1, wh_wT2, 256, 64, 256);
    cvt_taps<<<(147456 + 255) / 256, 256, 0, stream>>>(hm_w1, hm_wT2, 256, 64, 256);
    cvt_taps<<<(1032192 + 255) / 256, 256, 0, stream>>>(id_w1, id_wT2, 256, 448, 256);
    cvt_taps<<<(762048 + 255) / 256, 256, 0, stream>>>(off_w, off_wT2, 189, 448, 192);
    cvt_flat<<<(512 + 255) / 256, 256, 0, stream>>>(wh_w2, wh_w2b, 512);
    cvt_flat<<<(6144 + 255) / 256, 256, 0, stream>>>(hm_w2, hm_w2b, 6144);
    cvt_flat<<<(32768 + 255) / 256, 256, 0, stream>>>(id_w2, id_w2b, 32768);
    cvt_flat<<<(4096 + 255) / 256, 256, 0, stream>>>(bz_w, bz_wb, 4096);
    cvt_dcnA<<<(1032192 + 255) / 256, 256, 0, stream>>>(dcn_w, dcn_wA);

    // 2) MFMA conv branches (staging from channels-last X2)
    conv3x3_mfma<4, 1><<<dim3(96, 28), 256, 0, stream>>>(
        X2, wh_wT2, wh_b1, wh_w2b, wh_b2, out_wh, 64, 256, 2, 0, 1);
    conv3x3_mfma<4, 0><<<dim3(96, 4), 256, 0, stream>>>(
        X2, hm_wT2, hm_b1, hm_w2b, hm_b2, out_hm, 64, 256, 24, 192, 0);
    conv3x3_mfma<4, 0><<<dim3(96, 4), 256, 0, stream>>>(
        X2, id_wT2, id_b1, id_w2b, id_b2, out_id, 448, 256, 128, 0, 0);
    conv3x3_mfma<3, 2><<<dim3(96, 4), 256, 0, stream>>>(
        X2, off_wT2, off_b, nullptr, nullptr, off_out, 448, 192, 189, 0, 0);

    // 3) DCN via MFMA + BN + ReLU + bz (consumes off_out + X2)
    dcn_bz_mfma<<<dim3(192, 4), 256, 0, stream>>>(
        X2, off_out, dcn_wA, dcn_b, bn_g, bn_be, bn_mn, bn_vr,
        bz_wb, bz_b, out_bz);
}